// Round 2
// 177.593 us; speedup vs baseline: 1.0445x; 1.0445x over previous
//
#include <hip/hip_runtime.h>
#include <hip/hip_bf16.h>
#include <math.h>

#define NN 4096
#define NC 128
#define NH 8
#define NV 16
#define NB 4
#define BD 64   // NB*NV

typedef _Float16 half8 __attribute__((ext_vector_type(8)));
typedef __fp16  fp16x2 __attribute__((ext_vector_type(2)));
typedef float floatx4 __attribute__((ext_vector_type(4)));

__device__ __forceinline__ int get_loc(const int* locp){
    int lr = locp[0];
    return (lr >= 0 && lr <= 100) ? lr : 64;
}
__device__ __forceinline__ float head_scale(const float* rr, int h){
    float ts = tanf(0.78539816339744831f * (1.0f + sinf(rr[h])));
    if (!(ts > 0.f)) ts = (ts == 0.f) ? 1e-20f : 1e20f;
    if (ts > 1e20f) ts = 1e20f;
    return ts;
}
// barrier that drains LDS only — leaves global loads (vmcnt) in flight.
__device__ __forceinline__ void lds_barrier(){
    __asm__ __volatile__("s_waitcnt lgkmcnt(0)\n\ts_barrier" ::: "memory");
}

// ---------------------------------------------------------------------------
// K1: per row i of dist (f32 in [0,1)): Kval_i = rank-th smallest
// (rank = floor(loc*(N-1)/100)+1), xmin_i = row min.  (unchanged)
// ---------------------------------------------------------------------------
__global__ __launch_bounds__(256) void k_rowstats(const float* __restrict__ dist,
                                                  const int* __restrict__ locp,
                                                  float* __restrict__ Kval,
                                                  float* __restrict__ xminp){
    __shared__ unsigned int hist[4][256];
    __shared__ float cand[1024];
    __shared__ unsigned int cnt, selb_s, basec_s, xminu;
    const int i = blockIdx.x, t = threadIdx.x;
    const int wv = t >> 6, lane = t & 63;
    const int loc = get_loc(locp);
    const unsigned int rank = (unsigned int)(((long long)loc * (NN - 1)) / 100) + 1u;

    float v[16];
    const float4* rp = (const float4*)(dist + (size_t)i * NN);
#pragma unroll
    for (int k = 0; k < 4; k++){
        float4 x4 = rp[k * 256 + t];
        v[4*k+0] = x4.x; v[4*k+1] = x4.y; v[4*k+2] = x4.z; v[4*k+3] = x4.w;
    }
    for (int k = t; k < 1024; k += 256) ((unsigned int*)hist)[k] = 0;
    if (t == 0){ cnt = 0; selb_s = 255u; basec_s = 0u; xminu = 0xFFFFFFFFu; }
    __syncthreads();

    float lmin = 1e30f;
#pragma unroll
    for (int u = 0; u < 16; u++){
        float x = v[u];
        lmin = fminf(lmin, x);
        int b = (int)(x * 256.0f); b = b < 0 ? 0 : (b > 255 ? 255 : b);
        atomicAdd(&hist[wv][b], 1u);
    }
#pragma unroll
    for (int off = 1; off < 64; off <<= 1) lmin = fminf(lmin, __shfl_xor(lmin, off));
    if (lane == 0) atomicMin(&xminu, __float_as_uint(lmin));
    __syncthreads();

    if (t < 64){
        unsigned int lp[4];
        unsigned int run = 0;
#pragma unroll
        for (int q = 0; q < 4; q++){
            int b = 4 * t + q;
            run += hist[0][b] + hist[1][b] + hist[2][b] + hist[3][b];
            lp[q] = run;
        }
        unsigned int incl = run;
#pragma unroll
        for (int d = 1; d < 64; d <<= 1){
            unsigned int y = __shfl_up(incl, d);
            if (t >= d) incl += y;
        }
        unsigned int excl = incl - run;
        if (excl < rank && rank <= incl){
#pragma unroll
            for (int q = 0; q < 4; q++){
                if (excl + lp[q] >= rank){
                    selb_s  = (unsigned int)(4 * t + q);
                    basec_s = excl + (q ? lp[q-1] : 0u);
                    break;
                }
            }
        }
    }
    __syncthreads();
    const unsigned int sb = selb_s;
    if (t == 0) Kval[i] = ((float)sb + 1.0f) * 0.00390625f;   // fallback, overwritten below
#pragma unroll
    for (int u = 0; u < 16; u++){
        float x = v[u];
        int b = (int)(x * 256.0f); b = b < 0 ? 0 : (b > 255 ? 255 : b);
        if ((unsigned int)b == sb){
            unsigned int idx = atomicAdd(&cnt, 1u);
            if (idx < 1024u) cand[idx] = x;
        }
    }
    __syncthreads();
    const unsigned int n = cnt > 1024u ? 1024u : cnt;
    const unsigned int need = rank - basec_s;
    for (unsigned int c0 = t; c0 < n; c0 += 256){
        float x = cand[c0];
        unsigned int lt = 0, le = 0;
        for (unsigned int k2 = 0; k2 < n; k2++){
            float y = cand[k2];
            lt += (y < x); le += (y <= x);
        }
        if (lt < need && need <= le) Kval[i] = x;
    }
    if (t == 0) xminp[i] = __uint_as_float(xminu);
}

// ---------------------------------------------------------------------------
// K2: val_t[h][bd][j] = sum_c in[b][j][c] * wgt[h][c][d], bd = b*16+d, f16.
// (unchanged)
// ---------------------------------------------------------------------------
__global__ __launch_bounds__(256) void k_value(const float* __restrict__ in,
                                               const float* __restrict__ wgt,
                                               _Float16* __restrict__ val_t){
    __shared__ float insh[NC * 65];
    __shared__ float wsh[NC * NV];
    const int j0 = blockIdx.x * 16;
    const int h  = blockIdx.y;
    const int t  = threadIdx.x;

    for (int k = t; k < NC * NV; k += 256) wsh[k] = wgt[h * NC * NV + k];
#pragma unroll
    for (int k = 0; k < 32; k++){
        int idx = k * 256 + t;
        int p = idx >> 7, c = idx & 127;
        int b = p >> 4, jl = p & 15;
        insh[c * 65 + jl * 4 + b] = in[((size_t)b * NN + j0 + jl) * NC + c];
    }
    __syncthreads();

    const int r = t & 63, dq = t >> 6;
    const int jl = r >> 2, b = r & 3;
    float a0 = 0.f, a1 = 0.f, a2 = 0.f, a3 = 0.f;
#pragma unroll 8
    for (int c = 0; c < NC; c++){
        float x = insh[c * 65 + r];
        float4 w4 = *(const float4*)&wsh[c * NV + dq * 4];
        a0 = fmaf(x, w4.x, a0);
        a1 = fmaf(x, w4.y, a1);
        a2 = fmaf(x, w4.z, a2);
        a3 = fmaf(x, w4.w, a3);
    }
    const size_t base = ((size_t)(h * BD + b * NV + dq * 4)) * NN + j0 + jl;
    val_t[base         ] = (_Float16)a0;
    val_t[base + NN    ] = (_Float16)a1;
    val_t[base + 2 * NN] = (_Float16)a2;
    val_t[base + 3 * NN] = (_Float16)a3;
}

// ---------------------------------------------------------------------------
// K3 (MFMA): 32-i tiles, grid (NN/32, NH) = 1024 blocks.
//   (a) 2-deep register prefetch (sets A/B, loop unrolled x2): issue->use
//       slack grows from ~1 MFMA phase to a full tile phase, covering
//       L2/L3 load latency (kernel was latency-bound: VALU 49%/MFMA 14%).
//   (b) XCD-aware remap: the 8 head-blocks sharing an i-tile become
//       temporally adjacent on one XCD -> dist tile gets 8x L2 reuse
//       (working set 4 tiles x 512KB = 2MB < 4MB per-XCD L2).
//   (c) staging VALU cut: mask folded into exp2 argument (cndmask before
//       exp2), f32->f16 via v_cvt_pkrtz pairs instead of 8 cvt + packs.
// ---------------------------------------------------------------------------
__global__ __launch_bounds__(256) void k_att(const float* __restrict__ dist,
                                             const float* __restrict__ rr,
                                             const _Float16* __restrict__ val_t,
                                             const float* __restrict__ Kvalp,
                                             const float* __restrict__ xminp,
                                             float* __restrict__ out){
    __shared__ alignas(16) _Float16 wtile[2][32 * 72];   // [i][j]  2 x 4.6 KB
    __shared__ alignas(16) _Float16 vtile[2][64 * 72];   // [bd][j] 2 x 9.2 KB

    // XCD remap: linear id l -> xcd = l&7 (round-robin dispatch), slot s.
    // Within an XCD, h varies fastest -> concurrent set = 4 i-tiles x 8 h.
    const int l   = blockIdx.x + (NN / 32) * blockIdx.y;   // 0..1023
    const int xcd = l & 7;
    const int s   = l >> 3;                                // 0..127
    const int i0  = (xcd * 16 + (s >> 3)) * 32;
    const int h   = s & 7;

    const int t = threadIdx.x;
    const int lane = t & 63, wv = t >> 6;
    const float ts  = head_scale(rr, h);
    const float ts2 = ts * 1.44269504088896f;   // exp(a) = exp2(a*log2e)

    // staging roles (fixed per thread)
    const int il = t >> 3, jq = t & 7;          // w-stage: row il, 8 j's
    const int vrow = t >> 3, vpart = t & 7;     // v-stage: rows vrow, vrow+32
    const float kvi  = Kvalp[i0 + il];
    const float txmi = ts2 * xminp[i0 + il];
    const float nts2 = -ts2;

    half8 ones;
#pragma unroll
    for (int u = 0; u < 8; u++) ones[u] = (_Float16)1.0f;

    const float* dp = dist + (size_t)(i0 + il) * NN + jq * 8;
    const _Float16* vp0 = val_t + (size_t)(h * BD + vrow) * NN + vpart * 8;
    const _Float16* vp1 = vp0 + (size_t)32 * NN;

    floatx4 acc0 = (floatx4){0.f,0.f,0.f,0.f};
    floatx4 acc1 = (floatx4){0.f,0.f,0.f,0.f};
    floatx4 accs = (floatx4){0.f,0.f,0.f,0.f};

    const int is16 = (wv & 1) * 16;
    const int bh   = (wv >> 1) * 32;
    const int aoff  = (is16 + (lane & 15)) * 72 + (lane >> 4) * 8;
    const int boff0 = (bh + (lane & 15)) * 72 + (lane >> 4) * 8;
    const int boff1 = boff0 + 16 * 72;
    const int voff0 = vrow * 72 + vpart * 8;
    const int voff1 = (vrow + 32) * 72 + vpart * 8;
    const int woff  = il * 72 + jq * 8;

    uint4  Av0, Av1, Bv0, Bv1;
    float4 Ad0, Ad1, Bd0, Bd1;

#define LOADSET(V0, V1, D0, D1) do{                                          \
        V0 = *(const uint4*)vp0;  vp0 += 64;                                 \
        V1 = *(const uint4*)vp1;  vp1 += 64;                                 \
        D0 = *(const float4*)dp;                                             \
        D1 = *(const float4*)(dp + 4);  dp += 64; }while(0)

#define STAGE(BUF, V0, V1, D0, D1) do{                                       \
        *(uint4*)&vtile[BUF][voff0] = V0;                                    \
        *(uint4*)&vtile[BUF][voff1] = V1;                                    \
        const float dd_[8] = {D0.x,D0.y,D0.z,D0.w,D1.x,D1.y,D1.z,D1.w};      \
        union { half8 h8; fp16x2 h2[4]; } uu_;                               \
        _Pragma("unroll")                                                    \
        for (int u_ = 0; u_ < 4; u_++){                                      \
            float a0_ = fmaf(nts2, dd_[2*u_  ], txmi);                       \
            float a1_ = fmaf(nts2, dd_[2*u_+1], txmi);                       \
            a0_ = (dd_[2*u_  ] <= kvi) ? a0_ : -20000.0f;                    \
            a1_ = (dd_[2*u_+1] <= kvi) ? a1_ : -20000.0f;                    \
            uu_.h2[u_] = __builtin_amdgcn_cvt_pkrtz(                         \
                __builtin_amdgcn_exp2f(a0_), __builtin_amdgcn_exp2f(a1_));   \
        }                                                                    \
        *(half8*)&wtile[BUF][woff] = uu_.h8; }while(0)

#define MFMA_T(BUF) do{                                                      \
        _Pragma("unroll")                                                    \
        for (int kc_ = 0; kc_ < 2; kc_++){                                   \
            half8 af = *(const half8*)&wtile[BUF][aoff  + kc_ * 32];         \
            half8 b0 = *(const half8*)&vtile[BUF][boff0 + kc_ * 32];         \
            half8 b1 = *(const half8*)&vtile[BUF][boff1 + kc_ * 32];         \
            acc0 = __builtin_amdgcn_mfma_f32_16x16x32_f16(af, b0, acc0, 0, 0, 0); \
            acc1 = __builtin_amdgcn_mfma_f32_16x16x32_f16(af, b1, acc1, 0, 0, 0); \
            accs = __builtin_amdgcn_mfma_f32_16x16x32_f16(af, ones, accs, 0, 0, 0); \
        } }while(0)

    // ---- prologue: t0 -> A, t1 -> B; stage t0 into buf0
    LOADSET(Av0, Av1, Ad0, Ad1);
    LOADSET(Bv0, Bv1, Bd0, Bd1);
    STAGE(0, Av0, Av1, Ad0, Ad1);

    // ---- main: tiles (2jp, 2jp+1); prefetch 2jp+2 -> A, 2jp+3 -> B.
    // One LDS-only barrier per tile; 2 register sets keep 8 global loads
    // in flight so staging never waits on a fresh load.
    for (int jp = 0; jp < 31; jp++){
        LOADSET(Av0, Av1, Ad0, Ad1);          // tile 2jp+2
        lds_barrier();
        MFMA_T(0);                             // tile 2jp   (buf0)
        STAGE(1, Bv0, Bv1, Bd0, Bd1);          // tile 2jp+1 -> buf1
        LOADSET(Bv0, Bv1, Bd0, Bd1);          // tile 2jp+3
        lds_barrier();
        MFMA_T(1);                             // tile 2jp+1 (buf1)
        STAGE(0, Av0, Av1, Ad0, Ad1);          // tile 2jp+2 -> buf0
    }
    // ---- tail: tiles 62 (buf0, already staged) and 63 (in B)
    lds_barrier();
    MFMA_T(0);                                 // tile 62
    STAGE(1, Bv0, Bv1, Bd0, Bd1);              // tile 63 -> buf1
    lds_barrier();
    MFMA_T(1);                                 // tile 63

#undef LOADSET
#undef STAGE
#undef MFMA_T

    // epilogue: D[m][n]: m=(lane>>4)*4+reg, n=lane&15; accs holds row-sums S
    const int m0 = (lane >> 4) * 4;
    const int d  = lane & 15;
#pragma unroll
    for (int r4 = 0; r4 < 4; r4++){
        const int iloc = is16 + m0 + r4;
        const float inv_s = 1.0f / fmaxf(accs[r4], 1e-30f);
#pragma unroll
        for (int nt = 0; nt < 2; nt++){
            const int b = (wv >> 1) * 2 + nt;
            float c = acc0[r4], c1 = acc1[r4];
            float cc = (nt == 0 ? c : c1) * inv_s;
            float g = 0.5f * cc * (1.0f + erff(cc * 0.70710678118654752f));
            out[((size_t)b * NN + i0 + iloc) * (NH * NV) + h * NV + d] = g;
        }
    }
}

// ---------------------------------------------------------------------------
extern "C" void kernel_launch(void* const* d_in, const int* in_sizes, int n_in,
                              void* d_out, int out_size, void* d_ws, size_t ws_size,
                              hipStream_t stream) {
    const float* in   = (const float*)d_in[0]; // (B,N,C) f32
    const float* dist = (const float*)d_in[1]; // (N,N) f32
    const float* r    = (const float*)d_in[2]; // (H,1,1) f32
    const float* wgt  = (const float*)d_in[3]; // (H,C,V) f32
    const int*   loc  = (const int*)d_in[4];   // scalar int
    float* out = (float*)d_out;                // (B,N,H*V) f32

    float* Kval = (float*)d_ws;
    float* xmin = Kval + NN;
    _Float16* val_t = (_Float16*)((char*)d_ws + 2 * (size_t)NN * sizeof(float)); // 4 MB

    k_rowstats<<<NN, 256, 0, stream>>>(dist, loc, Kval, xmin);
    k_value<<<dim3(NN / 16, NH), 256, 0, stream>>>(in, wgt, val_t);
    k_att<<<dim3(NN / 32, NH), 256, 0, stream>>>(dist, r, val_t, Kval, xmin, out);
}